// Round 3
// baseline (41.858 us; speedup 1.0000x reference)
//
#include <hip/hip_runtime.h>
#include <stdint.h>

// Gumbel-max sampler, fused, latency-optimized.
// Phase 1: grid = (32 segs, 256 rows), block = 256 threads. Each thread handles
//   exactly 4 float4s per operand (8 independent loads in flight) -> partial
//   argmax key per block into ws[seg*B + row].
// Phase 2: 1 block reduces 32 keys/row -> token id.
//
// score'[v] = logits[v]*(1/(t*ln2)) - log2(max(-log2(u[v]), 1e-10/ln2))
// monotone transform of reference score => identical argmax.
// Greedy rows (t<=1e-10): score'[v] = logits[v].

#define T1 256
#define SEGF4 1024   // float4s per block = T1 * 4

__device__ __forceinline__ uint32_t order_f32(float f) {
    uint32_t u = __float_as_uint(f);
    return (u & 0x80000000u) ? ~u : (u | 0x80000000u);
}

__device__ __forceinline__ void upd(float s, int idx, float& best, int& bidx) {
    if (s > best || (s == best && idx < bidx)) { best = s; bidx = idx; }
}

__global__ __launch_bounds__(T1) void sampler_part_kernel(
        const float* __restrict__ logits,
        const float* __restrict__ temps,
        const float* __restrict__ u,
        unsigned long long* __restrict__ ws,
        int V, int B) {
    const int seg = blockIdx.x;
    const int row = blockIdx.y;
    const int nvec = V >> 2;
    const int lim = nvec - 1;
    const int tid = threadIdx.x;

    // 4 strided, clamped vector indices (duplicate scans are argmax-neutral:
    // we always record the TRUE index of the element actually loaded)
    const int i0 = (seg * SEGF4) + tid;
    int ia = i0           > lim ? lim : i0;
    int ib = i0 + T1      > lim ? lim : i0 + T1;
    int ic = i0 + 2 * T1  > lim ? lim : i0 + 2 * T1;
    int id = i0 + 3 * T1  > lim ? lim : i0 + 3 * T1;

    const float t = temps[row];
    const bool greedy = (t <= 1e-10f);
    const float invT = greedy ? 1.0f : (1.4426950408889634f / t);
    const float CLMP = 1.4426950408889634e-10f;  // 1e-10 / ln2

    const size_t rowoff = (size_t)row * (size_t)V;
    const float4* lrow = reinterpret_cast<const float4*>(logits + rowoff);

    float best = -__builtin_inff();
    int bidx = 0x7fffffff;

    if (greedy) {
        float4 la = lrow[ia], lb = lrow[ib], lc = lrow[ic], ld = lrow[id];
        upd(la.x, 4*ia+0, best, bidx); upd(la.y, 4*ia+1, best, bidx);
        upd(la.z, 4*ia+2, best, bidx); upd(la.w, 4*ia+3, best, bidx);
        upd(lb.x, 4*ib+0, best, bidx); upd(lb.y, 4*ib+1, best, bidx);
        upd(lb.z, 4*ib+2, best, bidx); upd(lb.w, 4*ib+3, best, bidx);
        upd(lc.x, 4*ic+0, best, bidx); upd(lc.y, 4*ic+1, best, bidx);
        upd(lc.z, 4*ic+2, best, bidx); upd(lc.w, 4*ic+3, best, bidx);
        upd(ld.x, 4*id+0, best, bidx); upd(ld.y, 4*id+1, best, bidx);
        upd(ld.z, 4*id+2, best, bidx); upd(ld.w, 4*id+3, best, bidx);
    } else {
        const float4* urow = reinterpret_cast<const float4*>(u + rowoff);
        // issue all 8 loads before any use
        float4 la = lrow[ia], lb = lrow[ib], lc = lrow[ic], ld = lrow[id];
        float4 ua = urow[ia], ub = urow[ib], uc = urow[ic], ud = urow[id];
        float s;
        s = la.x * invT - __log2f(fmaxf(-__log2f(ua.x), CLMP)); upd(s, 4*ia+0, best, bidx);
        s = la.y * invT - __log2f(fmaxf(-__log2f(ua.y), CLMP)); upd(s, 4*ia+1, best, bidx);
        s = la.z * invT - __log2f(fmaxf(-__log2f(ua.z), CLMP)); upd(s, 4*ia+2, best, bidx);
        s = la.w * invT - __log2f(fmaxf(-__log2f(ua.w), CLMP)); upd(s, 4*ia+3, best, bidx);
        s = lb.x * invT - __log2f(fmaxf(-__log2f(ub.x), CLMP)); upd(s, 4*ib+0, best, bidx);
        s = lb.y * invT - __log2f(fmaxf(-__log2f(ub.y), CLMP)); upd(s, 4*ib+1, best, bidx);
        s = lb.z * invT - __log2f(fmaxf(-__log2f(ub.z), CLMP)); upd(s, 4*ib+2, best, bidx);
        s = lb.w * invT - __log2f(fmaxf(-__log2f(ub.w), CLMP)); upd(s, 4*ib+3, best, bidx);
        s = lc.x * invT - __log2f(fmaxf(-__log2f(uc.x), CLMP)); upd(s, 4*ic+0, best, bidx);
        s = lc.y * invT - __log2f(fmaxf(-__log2f(uc.y), CLMP)); upd(s, 4*ic+1, best, bidx);
        s = lc.z * invT - __log2f(fmaxf(-__log2f(uc.z), CLMP)); upd(s, 4*ic+2, best, bidx);
        s = lc.w * invT - __log2f(fmaxf(-__log2f(uc.w), CLMP)); upd(s, 4*ic+3, best, bidx);
        s = ld.x * invT - __log2f(fmaxf(-__log2f(ud.x), CLMP)); upd(s, 4*id+0, best, bidx);
        s = ld.y * invT - __log2f(fmaxf(-__log2f(ud.y), CLMP)); upd(s, 4*id+1, best, bidx);
        s = ld.z * invT - __log2f(fmaxf(-__log2f(ud.z), CLMP)); upd(s, 4*id+2, best, bidx);
        s = ld.w * invT - __log2f(fmaxf(-__log2f(ud.w), CLMP)); upd(s, 4*id+3, best, bidx);
    }

    // pack: high 32 = ordered score, low 32 = ~idx (max => first-index tie-break)
    unsigned long long key =
        ((unsigned long long)order_f32(best) << 32) | (unsigned long long)(~(uint32_t)bidx);

    #pragma unroll
    for (int off = 32; off > 0; off >>= 1) {
        unsigned long long other = __shfl_down(key, off, 64);
        if (other > key) key = other;
    }

    __shared__ unsigned long long smax;
    if (threadIdx.x == 0) smax = 0ull;
    __syncthreads();
    if ((threadIdx.x & 63) == 0) atomicMax(&smax, key);
    __syncthreads();
    if (threadIdx.x == 0) ws[(size_t)seg * B + row] = smax;
}

__global__ __launch_bounds__(256) void sampler_reduce_kernel(
        const unsigned long long* __restrict__ ws,
        int* __restrict__ out,
        int nseg, int B) {
    const int row = threadIdx.x;
    unsigned long long best = 0ull;
    #pragma unroll 8
    for (int s = 0; s < nseg; ++s) {
        unsigned long long k = ws[(size_t)s * B + row];  // coalesced across rows
        if (k > best) best = k;
    }
    out[row] = (int)(~(uint32_t)(best & 0xffffffffull));
}

extern "C" void kernel_launch(void* const* d_in, const int* in_sizes, int n_in,
                              void* d_out, int out_size, void* d_ws, size_t ws_size,
                              hipStream_t stream) {
    const float* logits = (const float*)d_in[0];
    const float* temps  = (const float*)d_in[1];
    const float* u      = (const float*)d_in[2];
    int* out = (int*)d_out;
    unsigned long long* ws = (unsigned long long*)d_ws;

    const int B = in_sizes[1];
    const int V = in_sizes[0] / B;
    const int nvec = V >> 2;
    const int nseg = (nvec + SEGF4 - 1) / SEGF4;   // 32 for V=128256

    dim3 grid(nseg, B);
    sampler_part_kernel<<<grid, T1, 0, stream>>>(logits, temps, u, ws, V, B);
    sampler_reduce_kernel<<<1, B, 0, stream>>>(ws, out, nseg, B);
}